// Round 1
// baseline (39.726 us; speedup 1.0000x reference)
//
#include <hip/hip_runtime.h>

// SmartCNN: 2048-board preprocess + two tiny convs, fused into one kernel.
// Per board b: read 16 f32, emit 96 f32. Memory-bound (117 MB round trip).

__device__ __forceinline__ int cls2(float v, bool fv, bool fh) {
    // value -> scrambled channel index *2 (pre-scaled for [c][k] lookup)
    int e = (v == 0.0f) ? 0 : (int)((__float_as_uint(v) >> 23) & 0xFFu) - 127;
    int c;
    if (e == 0)      c = fv ? 0 : 1;   // empty-cell channel (swapped with mask if fv)
    else if (e == 1) c = fh ? 3 : 2;   // class-1/class-2 swap if fh
    else if (e == 2) c = fh ? 2 : 3;
    else             c = 1 + e;
    return 2 * c;
}

__global__ __launch_bounds__(256) void smartcnn_kernel(
    const float* __restrict__ x,
    const float* __restrict__ W0,
    const float* __restrict__ b0,
    const float* __restrict__ W1,
    float* __restrict__ out,
    int B)
{
    __shared__ float sW0[96];  // [o][c][kw] : o*24 + c*2 + kw
    __shared__ float sW1[96];  // [o][c][kh] : o*24 + c*2 + kh
    __shared__ float sb0[4];

    int t = threadIdx.x;
    if (t < 96) { sW0[t] = W0[t]; sW1[t] = W1[t]; }
    if (t < 4)  { sb0[t] = b0[t]; }
    __syncthreads();

    int b = blockIdx.x * blockDim.x + t;
    if (b >= B) return;

    // ---- load board: 4x float4 (64 B contiguous per thread) ----
    const float4* x4 = (const float4*)x + (size_t)b * 4;
    float4 r0 = x4[0];
    float4 r1 = x4[1];
    float4 r2 = x4[2];
    float4 r3 = x4[3];

    // ---- corner argmax (first-max wins, like jnp.argmax) ----
    float best = r0.x; int ix = 0;
    if (r0.w > best) { best = r0.w; ix = 1; }
    if (r3.x > best) { best = r3.x; ix = 2; }
    if (r3.w > best) { best = r3.w; ix = 3; }
    bool fv = ix >= 2;
    bool fh = (ix & 1) != 0;

    // ---- apply flips (static indexing only) ----
    float4 a0 = fv ? r3 : r0;
    float4 a1 = fv ? r2 : r1;
    float4 a2 = fv ? r1 : r2;
    float4 a3 = fv ? r0 : r3;
    if (fh) {
        a0 = make_float4(a0.w, a0.z, a0.y, a0.x);
        a1 = make_float4(a1.w, a1.z, a1.y, a1.x);
        a2 = make_float4(a2.w, a2.z, a2.y, a2.x);
        a3 = make_float4(a3.w, a3.z, a3.y, a3.x);
    }

    // ---- per-cell value-channel index (*2), compile-time-indexed array ----
    int vc[16];
    vc[ 0] = cls2(a0.x, fv, fh); vc[ 1] = cls2(a0.y, fv, fh);
    vc[ 2] = cls2(a0.z, fv, fh); vc[ 3] = cls2(a0.w, fv, fh);
    vc[ 4] = cls2(a1.x, fv, fh); vc[ 5] = cls2(a1.y, fv, fh);
    vc[ 6] = cls2(a1.z, fv, fh); vc[ 7] = cls2(a1.w, fv, fh);
    vc[ 8] = cls2(a2.x, fv, fh); vc[ 9] = cls2(a2.y, fv, fh);
    vc[10] = cls2(a2.z, fv, fh); vc[11] = cls2(a2.w, fv, fh);
    vc[12] = cls2(a3.x, fv, fh); vc[13] = cls2(a3.y, fv, fh);
    vc[14] = cls2(a3.z, fv, fh); vc[15] = cls2(a3.w, fv, fh);
#define VC(i, j) vc[(i) * 4 + (j)]

    int mc2 = fv ? 2 : 0;  // mask channel index *2

    // per-output-channel constants (mask contribution folded in)
    float C0[4], C1[4];
#pragma unroll
    for (int o = 0; o < 4; ++o) {
        int o24 = o * 24;
        C0[o] = sb0[o] + sW0[o24 + mc2] + sW0[o24 + mc2 + 1];
        C1[o] =          sW1[o24 + mc2] + sW1[o24 + mc2 + 1];
    }

    float4* out4 = (float4*)out + (size_t)b * 24;

    // ---- zh = relu(conv(p, W0) + b0): out[b,0,o,i,j], i 0..3, j 0..2 ----
#pragma unroll
    for (int o = 0; o < 4; ++o) {
        int o24 = o * 24;
        float v[12];
#pragma unroll
        for (int i = 0; i < 4; ++i) {
#pragma unroll
            for (int j = 0; j < 3; ++j) {
                float s = C0[o] + sW0[o24 + VC(i, j)] + sW0[o24 + VC(i, j + 1) + 1];
                v[i * 3 + j] = fmaxf(s, 0.0f);
            }
        }
        out4[o * 3 + 0] = make_float4(v[0], v[1], v[2],  v[3]);
        out4[o * 3 + 1] = make_float4(v[4], v[5], v[6],  v[7]);
        out4[o * 3 + 2] = make_float4(v[8], v[9], v[10], v[11]);
    }

    // ---- zv^T: out[b,1,o,a,q] = zv[o,q,a] = relu(conv(p, W1)), q 0..2, a 0..3 ----
#pragma unroll
    for (int o = 0; o < 4; ++o) {
        int o24 = o * 24;
        float v[12];
#pragma unroll
        for (int a = 0; a < 4; ++a) {
#pragma unroll
            for (int q = 0; q < 3; ++q) {
                float s = C1[o] + sW1[o24 + VC(q, a)] + sW1[o24 + VC(q + 1, a) + 1];
                v[a * 3 + q] = fmaxf(s, 0.0f);
            }
        }
        out4[12 + o * 3 + 0] = make_float4(v[0], v[1], v[2],  v[3]);
        out4[12 + o * 3 + 1] = make_float4(v[4], v[5], v[6],  v[7]);
        out4[12 + o * 3 + 2] = make_float4(v[8], v[9], v[10], v[11]);
    }
#undef VC
}

extern "C" void kernel_launch(void* const* d_in, const int* in_sizes, int n_in,
                              void* d_out, int out_size, void* d_ws, size_t ws_size,
                              hipStream_t stream) {
    const float* x  = (const float*)d_in[0];
    const float* W0 = (const float*)d_in[1];
    const float* b0 = (const float*)d_in[2];
    const float* W1 = (const float*)d_in[3];
    float* out = (float*)d_out;

    int B = in_sizes[0] / 16;
    const int threads = 256;
    int blocks = (B + threads - 1) / threads;
    smartcnn_kernel<<<blocks, threads, 0, stream>>>(x, W0, b0, W1, out, B);
}

// Round 2
// 29.144 us; speedup vs baseline: 1.3631x; 1.3631x over previous
//
#include <hip/hip_runtime.h>

// SmartCNN: 2048-board preprocess + two tiny 12-ch convs, fused.
// Per board: read 64 B, write 384 B. Memory-bound target ~18.6 us @6.3 TB/s.
//
// Round-2 changes vs round-1 (39.7 us):
//  - packed float4 weight table: 1 ds_read_b128 per (cell,o) gives all 4 taps
//    (W0 tap0/tap1, W1 tap0/tap1)  -> 68 b128 reads vs 192 b32 reads/thread
//  - LDS-staged coalesced output: lane-contiguous 1KB global stores
//    (16 full 64B lines/instr) instead of 64 scattered lines/instr

__device__ __forceinline__ int cls(float v, bool fv, bool fh) {
    // raw tile value -> scrambled channel index (0..11) matching reference
    int e = (v == 0.0f) ? 0 : (int)((__float_as_uint(v) >> 23) & 0xFFu) - 127;
    if (e == 0) return fv ? 0 : 1;   // empty channel (swaps with mask if fv)
    if (e == 1) return fh ? 3 : 2;   // class 1/2 swap if fh
    if (e == 2) return fh ? 2 : 3;
    return 1 + e;
}

__global__ __launch_bounds__(64) void smartcnn_kernel(
    const float* __restrict__ x,
    const float* __restrict__ W0,
    const float* __restrict__ b0,
    const float* __restrict__ W1,
    float* __restrict__ out,
    int B)
{
    __shared__ float4 sW[48];          // [o*12+c] = {W0[o][c][0], W0[o][c][1], W1[o][c][0], W1[o][c][1]}
    __shared__ float  sB[4];
    __shared__ float4 stage[64 * 13];  // [board][12 used + 1 pad] -> conflict-free writer banks

    const int t = threadIdx.x;
    if (t < 48) sW[t] = make_float4(W0[t * 2], W0[t * 2 + 1], W1[t * 2], W1[t * 2 + 1]);
    if (t < 4)  sB[t] = b0[t];
    __syncthreads();

    const int b = blockIdx.x * 64 + t;
    const int B0 = blockIdx.x * 64;

    float4 zv4[12];   // zv kept in regs until zh half is flushed
    bool live = (b < B);

    if (live) {
        const float4* x4 = (const float4*)x + (size_t)b * 4;
        float4 r0 = x4[0], r1 = x4[1], r2 = x4[2], r3 = x4[3];

        // corner argmax, first-max wins (jnp.argmax semantics)
        float best = r0.x; int ix = 0;
        if (r0.w > best) { best = r0.w; ix = 1; }
        if (r3.x > best) { best = r3.x; ix = 2; }
        if (r3.w > best) { best = r3.w; ix = 3; }
        bool fv = ix >= 2;
        bool fh = (ix & 1) != 0;

        float4 a0 = fv ? r3 : r0;
        float4 a1 = fv ? r2 : r1;
        float4 a2 = fv ? r1 : r2;
        float4 a3 = fv ? r0 : r3;
        if (fh) {
            a0 = make_float4(a0.w, a0.z, a0.y, a0.x);
            a1 = make_float4(a1.w, a1.z, a1.y, a1.x);
            a2 = make_float4(a2.w, a2.z, a2.y, a2.x);
            a3 = make_float4(a3.w, a3.z, a3.y, a3.x);
        }

        int vc[16];
        vc[ 0] = cls(a0.x, fv, fh); vc[ 1] = cls(a0.y, fv, fh);
        vc[ 2] = cls(a0.z, fv, fh); vc[ 3] = cls(a0.w, fv, fh);
        vc[ 4] = cls(a1.x, fv, fh); vc[ 5] = cls(a1.y, fv, fh);
        vc[ 6] = cls(a1.z, fv, fh); vc[ 7] = cls(a1.w, fv, fh);
        vc[ 8] = cls(a2.x, fv, fh); vc[ 9] = cls(a2.y, fv, fh);
        vc[10] = cls(a2.z, fv, fh); vc[11] = cls(a2.w, fv, fh);
        vc[12] = cls(a3.x, fv, fh); vc[13] = cls(a3.y, fv, fh);
        vc[14] = cls(a3.z, fv, fh); vc[15] = cls(a3.w, fv, fh);

        const int mc = fv ? 1 : 0;  // mask channel (scrambled)
        float4* st = &stage[t * 13];

#pragma unroll
        for (int o = 0; o < 4; ++o) {
            float4 wm = sW[o * 12 + mc];
            float c0 = sB[o] + wm.x + wm.y;  // bias + mask contribution (mask=1 everywhere)
            float c1 = wm.z + wm.w;

            float4 tt[16];
#pragma unroll
            for (int cell = 0; cell < 16; ++cell) tt[cell] = sW[o * 12 + vc[cell]];

            // zh(o,i,j) = relu(c0 + W0[vc(i,j)][0] + W0[vc(i,j+1)][1])
            float hv[12];
#pragma unroll
            for (int i = 0; i < 4; ++i) {
#pragma unroll
                for (int j = 0; j < 3; ++j) {
                    hv[i * 3 + j] = fmaxf(c0 + tt[i * 4 + j].x + tt[i * 4 + j + 1].y, 0.0f);
                }
            }
            st[o * 3 + 0] = make_float4(hv[0], hv[1], hv[2],  hv[3]);
            st[o * 3 + 1] = make_float4(hv[4], hv[5], hv[6],  hv[7]);
            st[o * 3 + 2] = make_float4(hv[8], hv[9], hv[10], hv[11]);

            // zv^T(o,a,q) = relu(c1 + W1[vc(q,a)][0] + W1[vc(q+1,a)][1])
            float vv[12];
#pragma unroll
            for (int a = 0; a < 4; ++a) {
#pragma unroll
                for (int q = 0; q < 3; ++q) {
                    vv[a * 3 + q] = fmaxf(c1 + tt[q * 4 + a].z + tt[(q + 1) * 4 + a].w, 0.0f);
                }
            }
            zv4[o * 3 + 0] = make_float4(vv[0], vv[1], vv[2],  vv[3]);
            zv4[o * 3 + 1] = make_float4(vv[4], vv[5], vv[6],  vv[7]);
            zv4[o * 3 + 2] = make_float4(vv[8], vv[9], vv[10], vv[11]);
        }
    }
    __syncthreads();

    // cooperative coalesced write of zh half: 12 rounds x 1KB contiguous
    float4* out4 = (float4*)out;
#pragma unroll
    for (int r = 0; r < 12; ++r) {
        int g = r * 64 + t;
        int bd = g / 12;
        int wi = g - bd * 12;
        if (B0 + bd < B)
            out4[(size_t)(B0 + bd) * 24 + wi] = stage[bd * 13 + wi];
    }
    __syncthreads();

    // stage zv half
    if (live) {
        float4* st = &stage[t * 13];
#pragma unroll
        for (int s = 0; s < 12; ++s) st[s] = zv4[s];
    }
    __syncthreads();

#pragma unroll
    for (int r = 0; r < 12; ++r) {
        int g = r * 64 + t;
        int bd = g / 12;
        int wi = g - bd * 12;
        if (B0 + bd < B)
            out4[(size_t)(B0 + bd) * 24 + 12 + wi] = stage[bd * 13 + wi];
    }
}

extern "C" void kernel_launch(void* const* d_in, const int* in_sizes, int n_in,
                              void* d_out, int out_size, void* d_ws, size_t ws_size,
                              hipStream_t stream) {
    const float* x  = (const float*)d_in[0];
    const float* W0 = (const float*)d_in[1];
    const float* b0 = (const float*)d_in[2];
    const float* W1 = (const float*)d_in[3];
    float* out = (float*)d_out;

    int B = in_sizes[0] / 16;
    int blocks = (B + 63) / 64;
    smartcnn_kernel<<<blocks, 64, 0, stream>>>(x, W0, b0, W1, out, B);
}

// Round 3
// 24.346 us; speedup vs baseline: 1.6317x; 1.1970x over previous
//
#include <hip/hip_runtime.h>

// SmartCNN round 3: 4 lanes per board, zero LDS staging, zero barriers in
// the main path, minimal memory transactions.
//
// Mapping: lane quad q=0..3 of board b writes float4s m = 4r+q (r=0..5) at
// out4[b*24+m] -> every store instr = 16 full 64B lines. Flip scramble is
// folded into 4 flip-specialized weight tables in LDS; spatial flip into a
// cell-index XOR (fv:^12, fh:^3); per-cell classes into two packed nibble
// u32s (runtime cell index = bit-extract, never a register-array index).

__global__ __launch_bounds__(256) void smartcnn_kernel(
    const float* __restrict__ x,
    const float* __restrict__ W0,
    const float* __restrict__ b0,
    const float* __restrict__ W1,
    float* __restrict__ out,
    int B)
{
    // flip-specialized tables: idx = flip*44 + o*11 + e   (e = log2 class 0..10)
    __shared__ float tab0h[176], tab1h[176];  // W0 tap0 / tap1 (horizontal conv)
    __shared__ float tab0v[176], tab1v[176];  // W1 tap0 / tap1 (vertical conv)
    __shared__ float sC0[16], sC1[16];        // per (flip,o): bias + mask contribution

    const int t = threadIdx.x;
    if (t < 176) {
        int flip = t / 44, rem = t % 44, o = rem / 11, e = rem % 11;
        int fvv = flip >> 1, fhh = flip & 1;
        int ch;                              // scrambled channel for class e
        if (e == 0)      ch = fvv ? 0 : 1;   // empty (swaps with mask if fv)
        else if (e == 1) ch = fhh ? 3 : 2;   // class1/class2 swap if fh
        else if (e == 2) ch = fhh ? 2 : 3;
        else             ch = 1 + e;
        tab0h[t] = W0[o * 24 + ch * 2 + 0];
        tab1h[t] = W0[o * 24 + ch * 2 + 1];
        tab0v[t] = W1[o * 24 + ch * 2 + 0];
        tab1v[t] = W1[o * 24 + ch * 2 + 1];
    }
    if (t < 16) {
        int flip = t >> 2, o = t & 3, mcf = (flip >> 1) & 1;  // mask channel = fv?1:0
        sC0[t] = b0[o] + W0[o * 24 + mcf * 2] + W0[o * 24 + mcf * 2 + 1];
        sC1[t] =          W1[o * 24 + mcf * 2] + W1[o * 24 + mcf * 2 + 1];
    }
    __syncthreads();

    int gq = blockIdx.x * 256 + t;
    int b = gq >> 2;        // board
    int q = gq & 3;         // which float4 of each 64B output line
    if (b >= B) return;

    // load full board (quad lanes hit the same lines; L1 serves the re-reads)
    const float4* x4 = (const float4*)x + (size_t)b * 4;
    float4 r0 = x4[0], r1 = x4[1], r2 = x4[2], r3 = x4[3];

    // corner argmax on the ORIGINAL board (first-max wins)
    float best = r0.x; int ix = 0;
    if (r0.w > best) { best = r0.w; ix = 1; }
    if (r3.x > best) { best = r3.x; ix = 2; }
    if (r3.w > best) { best = r3.w; ix = 3; }
    const int flipsel = ix;                 // fv*2 + fh
    const int fv = ix >> 1, fh = ix & 1;
    const int M  = fv * 12 + fh * 3;        // flipped-cell -> orig-cell XOR mask
    const int fb = flipsel * 44;            // table base (entries)

    // packed nibble classes of the ORIGINAL board, cell = row*4+col
#define EVAL(v) (max((int)(__float_as_uint(v) >> 23) - 127, 0))
    unsigned pack0 = (unsigned)EVAL(r0.x)        | ((unsigned)EVAL(r0.y) << 4)  |
                     ((unsigned)EVAL(r0.z) << 8)  | ((unsigned)EVAL(r0.w) << 12) |
                     ((unsigned)EVAL(r1.x) << 16) | ((unsigned)EVAL(r1.y) << 20) |
                     ((unsigned)EVAL(r1.z) << 24) | ((unsigned)EVAL(r1.w) << 28);
    unsigned pack1 = (unsigned)EVAL(r2.x)        | ((unsigned)EVAL(r2.y) << 4)  |
                     ((unsigned)EVAL(r2.z) << 8)  | ((unsigned)EVAL(r2.w) << 12) |
                     ((unsigned)EVAL(r3.x) << 16) | ((unsigned)EVAL(r3.y) << 20) |
                     ((unsigned)EVAL(r3.z) << 24) | ((unsigned)EVAL(r3.w) << 28);
#undef EVAL

    // class of orig cell c (0..15)
#define EX(c) (int)(((c) < 8 ? pack0 : pack1) >> (((c) & 7) * 4) & 15u)

    float4* out4 = (float4*)out + (size_t)b * 24;

#pragma unroll
    for (int rp = 0; rp < 3; ++rp) {        // rp = r%3 ; handles zh (r=rp) and zv (r=rp+3)
        const int n  = rp * 4 + q;          // f4 index within 48-float half
        const int o  = (n * 11) >> 5;       // n/3 for n<12
        const int s  = n - 3 * o;           // sub-row 0..2
        const int f1 = (s == 2) ? 1 : 0;
        const int f2 = (s >= 1) ? 1 : 0;
        const int s5 = s * 5;
        const int base = fb + o * 11;

        // ---- zh: cells (i,j),(i,j+1) in flipped space; cf = 5s+c+carry ----
        {
            const float Ch = sC0[flipsel * 4 + o];
            int c0 = s5, c1 = s5 + 1 + f1, c2 = s5 + 2 + f2, c3 = s5 + 4;
            float4 val;
            val.x = fmaxf(Ch + tab0h[base + EX(c0 ^ M)] + tab1h[base + EX((c0 + 1) ^ M)], 0.f);
            val.y = fmaxf(Ch + tab0h[base + EX(c1 ^ M)] + tab1h[base + EX((c1 + 1) ^ M)], 0.f);
            val.z = fmaxf(Ch + tab0h[base + EX(c2 ^ M)] + tab1h[base + EX((c2 + 1) ^ M)], 0.f);
            val.w = fmaxf(Ch + tab0h[base + EX(c3 ^ M)] + tab1h[base + EX((c3 + 1) ^ M)], 0.f);
            out4[rp * 4 + q] = val;
        }
        // ---- zv^T: cells (qq,a),(qq+1,a); cf = 5s+4c-11*carry ----
        {
            const float Cv = sC1[flipsel * 4 + o];
            int c0 = s5, c1 = s5 + 4 - 11 * f1, c2 = s5 + 8 - 11 * f2, c3 = s5 + 1;
            float4 val;
            val.x = fmaxf(Cv + tab0v[base + EX(c0 ^ M)] + tab1v[base + EX((c0 + 4) ^ M)], 0.f);
            val.y = fmaxf(Cv + tab0v[base + EX(c1 ^ M)] + tab1v[base + EX((c1 + 4) ^ M)], 0.f);
            val.z = fmaxf(Cv + tab0v[base + EX(c2 ^ M)] + tab1v[base + EX((c2 + 4) ^ M)], 0.f);
            val.w = fmaxf(Cv + tab0v[base + EX(c3 ^ M)] + tab1v[base + EX((c3 + 4) ^ M)], 0.f);
            out4[12 + rp * 4 + q] = val;
        }
    }
#undef EX
}

extern "C" void kernel_launch(void* const* d_in, const int* in_sizes, int n_in,
                              void* d_out, int out_size, void* d_ws, size_t ws_size,
                              hipStream_t stream) {
    const float* x  = (const float*)d_in[0];
    const float* W0 = (const float*)d_in[1];
    const float* b0 = (const float*)d_in[2];
    const float* W1 = (const float*)d_in[3];
    float* out = (float*)d_out;

    int B = in_sizes[0] / 16;                 // boards
    int total = B * 4;                        // 4 lanes per board
    int blocks = (total + 255) / 256;
    smartcnn_kernel<<<blocks, 256, 0, stream>>>(x, W0, b0, W1, out, B);
}